// Round 1
// baseline (369.811 us; speedup 1.0000x reference)
//
#include <hip/hip_runtime.h>
#include <math.h>

// PillarAttentionClassifier — R1 baseline: fp32 vector, one thread per row.
// Strategy: full unroll, uniform weight indices -> s_load scalarization,
// BN folded to affine (precomputed into d_ws by a pre-kernel).
// Roofline: fp32-VALU-bound ~68us ideal; memory floor ~10us (future bf16-MFMA target).

#define EPS 1e-5f

// ---------------- BN affine precompute ----------------
// ws layout (floats): [0:96) enc_s, [96:192) enc_t, [192:256) s1, [256:320) t1,
//                     [320:352) s2, [352:384) t2, [384:400) s3, [400:416) t3
__global__ void bn_affine_kernel(
    const float* __restrict__ eg, const float* __restrict__ ebt,
    const float* __restrict__ em, const float* __restrict__ ev,
    const float* __restrict__ g1, const float* __restrict__ bb1,
    const float* __restrict__ m1, const float* __restrict__ v1,
    const float* __restrict__ g2, const float* __restrict__ bb2,
    const float* __restrict__ m2, const float* __restrict__ v2,
    const float* __restrict__ g3, const float* __restrict__ bb3,
    const float* __restrict__ m3, const float* __restrict__ v3,
    float* __restrict__ ws)
{
    int t = threadIdx.x;
    if (t < 96) {
        float s = eg[t] * rsqrtf(ev[t] + EPS);
        ws[t]      = s;
        ws[96 + t] = ebt[t] - em[t] * s;
    } else if (t < 160) {
        int c = t - 96;
        float s = g1[c] * rsqrtf(v1[c] + EPS);
        ws[192 + c] = s;
        ws[256 + c] = bb1[c] - m1[c] * s;
    } else if (t < 192) {
        int c = t - 160;
        float s = g2[c] * rsqrtf(v2[c] + EPS);
        ws[320 + c] = s;
        ws[352 + c] = bb2[c] - m2[c] * s;
    } else if (t < 208) {
        int c = t - 192;
        float s = g3[c] * rsqrtf(v3[c] + EPS);
        ws[384 + c] = s;
        ws[400 + c] = bb3[c] - m3[c] * s;
    }
}

// ---------------- main kernel ----------------
__global__ __launch_bounds__(256) void pillar_kernel(
    const float* __restrict__ x,
    const float* __restrict__ We, const float* __restrict__ be,
    const float* __restrict__ Wa, const float* __restrict__ ba,
    const float* __restrict__ W1, const float* __restrict__ b1,
    const float* __restrict__ W2, const float* __restrict__ b2,
    const float* __restrict__ W3, const float* __restrict__ b3,
    const float* __restrict__ W4, const float* __restrict__ b4,
    const float* __restrict__ aff,
    float* __restrict__ out, int B)
{
    int row = blockIdx.x * blockDim.x + threadIdx.x;
    if (row >= B) return;

    // ---- load input row (contiguous 116B per thread; L1/L2 absorbs) ----
    const float* xr = x + (long)row * 29;
    float xv[29];
    #pragma unroll
    for (int i = 0; i < 29; i++) xv[i] = xr[i];

    // ---- 12 pillar encoders: Linear + ReLU + BN-affine -> rep[96] ----
    constexpr int gstart[12] = {0, 3, 5, 7, 10, 12, 15, 17, 19, 20, 23, 26};
    constexpr int glen[12]   = {3, 2, 2, 3, 2, 3, 2, 2, 1, 3, 3, 3};
    float rep[96];
    #pragma unroll
    for (int g = 0; g < 12; g++) {
        #pragma unroll
        for (int o = 0; o < 8; o++) {
            float acc = be[g * 8 + o];
            #pragma unroll
            for (int i = 0; i < glen[g]; i++)
                acc = fmaf(xv[gstart[g] + i], We[(g * 3 + i) * 8 + o], acc);
            acc = fmaxf(acc, 0.0f);
            rep[g * 8 + o] = fmaf(acc, aff[g * 8 + o], aff[96 + g * 8 + o]);
        }
    }

    // ---- attention logits: rep[96] @ Wa[96,12] + ba ----
    float logit[12];
    #pragma unroll
    for (int g = 0; g < 12; g++) logit[g] = ba[g];
    #pragma unroll
    for (int k = 0; k < 96; k++) {
        float a = rep[k];
        #pragma unroll
        for (int g = 0; g < 12; g++)
            logit[g] = fmaf(a, Wa[k * 12 + g], logit[g]);
    }

    // ---- softmax over 12 ----
    float m = logit[0];
    #pragma unroll
    for (int g = 1; g < 12; g++) m = fmaxf(m, logit[g]);
    float sum = 0.0f;
    #pragma unroll
    for (int g = 0; g < 12; g++) { logit[g] = __expf(logit[g] - m); sum += logit[g]; }
    float inv = 1.0f / sum;
    #pragma unroll
    for (int g = 0; g < 12; g++) logit[g] *= inv;

    // ---- attended = rep * w (in place) ----
    #pragma unroll
    for (int k = 0; k < 96; k++) rep[k] *= logit[k >> 3];

    // ---- h1 = BNaffine(relu(attended @ W1[96,64] + b1)), two halves of 32 ----
    float h1[64];
    #pragma unroll
    for (int half = 0; half < 2; half++) {
        float acc[32];
        #pragma unroll
        for (int j = 0; j < 32; j++) acc[j] = b1[half * 32 + j];
        #pragma unroll
        for (int k = 0; k < 96; k++) {
            float a = rep[k];
            #pragma unroll
            for (int j = 0; j < 32; j++)
                acc[j] = fmaf(a, W1[k * 64 + half * 32 + j], acc[j]);
        }
        #pragma unroll
        for (int j = 0; j < 32; j++) {
            float r = fmaxf(acc[j], 0.0f);
            h1[half * 32 + j] = fmaf(r, aff[192 + half * 32 + j], aff[256 + half * 32 + j]);
        }
    }

    // ---- h2 = BNaffine(relu(h1 @ W2[64,32] + b2)) ----
    float h2[32];
    {
        float acc[32];
        #pragma unroll
        for (int j = 0; j < 32; j++) acc[j] = b2[j];
        #pragma unroll
        for (int k = 0; k < 64; k++) {
            float a = h1[k];
            #pragma unroll
            for (int j = 0; j < 32; j++)
                acc[j] = fmaf(a, W2[k * 32 + j], acc[j]);
        }
        #pragma unroll
        for (int j = 0; j < 32; j++) {
            float r = fmaxf(acc[j], 0.0f);
            h2[j] = fmaf(r, aff[320 + j], aff[352 + j]);
        }
    }

    // ---- h3 = BNaffine(relu(h2 @ W3[32,16] + b3)) ----
    float h3[16];
    {
        float acc[16];
        #pragma unroll
        for (int j = 0; j < 16; j++) acc[j] = b3[j];
        #pragma unroll
        for (int k = 0; k < 32; k++) {
            float a = h2[k];
            #pragma unroll
            for (int j = 0; j < 16; j++)
                acc[j] = fmaf(a, W3[k * 16 + j], acc[j]);
        }
        #pragma unroll
        for (int j = 0; j < 16; j++) {
            float r = fmaxf(acc[j], 0.0f);
            h3[j] = fmaf(r, aff[384 + j], aff[400 + j]);
        }
    }

    // ---- output: sigmoid(h3 @ W4 + b4) ----
    float z = b4[0];
    #pragma unroll
    for (int k = 0; k < 16; k++) z = fmaf(h3[k], W4[k], z);
    out[row] = 1.0f / (1.0f + __expf(-z));
}

extern "C" void kernel_launch(void* const* d_in, const int* in_sizes, int n_in,
                              void* d_out, int out_size, void* d_ws, size_t ws_size,
                              hipStream_t stream)
{
    const float* x   = (const float*)d_in[0];
    const float* We  = (const float*)d_in[1];
    const float* be  = (const float*)d_in[2];
    const float* eg  = (const float*)d_in[3];
    const float* ebt = (const float*)d_in[4];
    const float* em  = (const float*)d_in[5];
    const float* ev  = (const float*)d_in[6];
    const float* Wa  = (const float*)d_in[7];
    const float* ba  = (const float*)d_in[8];
    const float* W1  = (const float*)d_in[9];
    const float* b1  = (const float*)d_in[10];
    const float* g1  = (const float*)d_in[11];
    const float* bb1 = (const float*)d_in[12];
    const float* m1  = (const float*)d_in[13];
    const float* v1  = (const float*)d_in[14];
    const float* W2  = (const float*)d_in[15];
    const float* b2  = (const float*)d_in[16];
    const float* g2  = (const float*)d_in[17];
    const float* bb2 = (const float*)d_in[18];
    const float* m2  = (const float*)d_in[19];
    const float* v2  = (const float*)d_in[20];
    const float* W3  = (const float*)d_in[21];
    const float* b3  = (const float*)d_in[22];
    const float* g3  = (const float*)d_in[23];
    const float* bb3 = (const float*)d_in[24];
    const float* m3  = (const float*)d_in[25];
    const float* v3  = (const float*)d_in[26];
    const float* W4  = (const float*)d_in[27];
    const float* b4  = (const float*)d_in[28];

    int B = in_sizes[0] / 29;
    float* aff = (float*)d_ws;   // 416 floats

    bn_affine_kernel<<<1, 256, 0, stream>>>(eg, ebt, em, ev,
                                            g1, bb1, m1, v1,
                                            g2, bb2, m2, v2,
                                            g3, bb3, m3, v3, aff);

    int grid = (B + 255) / 256;
    pillar_kernel<<<grid, 256, 0, stream>>>(x, We, be, Wa, ba,
                                            W1, b1, W2, b2, W3, b3, W4, b4,
                                            aff, (float*)d_out, B);
}

// Round 2
// 197.362 us; speedup vs baseline: 1.8738x; 1.8738x over previous
//
#include <hip/hip_runtime.h>
#include <math.h>

// PillarAttentionClassifier — R2: fused per-wave MFMA pipeline, f16 in / fp32 acc.
// Each wave processes 16-row tiles end-to-end; 26 mfma_f32_16x16x32_f16 per tile.
// B-fragments (26 frags = 104 VGPRs) loaded once per block from global.
// Per-wave private LDS scratch for C-layout -> A-layout transforms; NO barriers.
// Layouts (per guide §3, m89/m120): A[m=lane&15][k=quad*8+j], B[k=quad*8+j][n=lane&15],
// C/D: col n=lane&15, row m=quad*4+reg.

typedef _Float16 f16x8 __attribute__((ext_vector_type(8)));
typedef float    f32x4 __attribute__((ext_vector_type(4)));

#define EPS 1e-5f

__device__ __forceinline__ float rcp_fast(float v) { return __builtin_amdgcn_rcpf(v); }

__host__ __device__ constexpr unsigned long long packGS() {
    constexpr int gs[12] = {0,3,5,7,10,12,15,17,19,20,23,26};
    unsigned long long v = 0;
    for (int g = 0; g < 12; ++g) v |= (unsigned long long)gs[g] << (5*g);
    return v;
}
__host__ __device__ constexpr unsigned packGL() {
    constexpr int gl[12] = {3,2,2,3,2,3,2,2,1,3,3,3};
    unsigned v = 0;
    for (int g = 0; g < 12; ++g) v |= (unsigned)gl[g] << (2*g);
    return v;
}

__global__ __launch_bounds__(256, 2) void fused_kernel(
    const float* __restrict__ x,
    const float* __restrict__ We,  const float* __restrict__ be,
    const float* __restrict__ eg,  const float* __restrict__ ebt,
    const float* __restrict__ em,  const float* __restrict__ ev,
    const float* __restrict__ Wa,  const float* __restrict__ ba,
    const float* __restrict__ W1,  const float* __restrict__ b1,
    const float* __restrict__ g1,  const float* __restrict__ bb1,
    const float* __restrict__ m1,  const float* __restrict__ v1,
    const float* __restrict__ W2,  const float* __restrict__ b2,
    const float* __restrict__ g2,  const float* __restrict__ bb2,
    const float* __restrict__ m2,  const float* __restrict__ v2,
    const float* __restrict__ W3,  const float* __restrict__ b3,
    const float* __restrict__ g3,  const float* __restrict__ bb3,
    const float* __restrict__ m3,  const float* __restrict__ v3,
    const float* __restrict__ W4,  const float* __restrict__ b4,
    float* __restrict__ out, int B, int ntiles)
{
    // per-wave private LDS scratch: 8192 B each, 4 waves = 32 KiB
    __shared__ __align__(16) char smem_raw[32768];
    const int lane = threadIdx.x & 63;
    const int wave = threadIdx.x >> 6;
    const int l15  = lane & 15;
    const int quad = lane >> 4;

    char* sw = smem_raw + wave * 8192;
    _Float16* repT = (_Float16*)(sw);          // [16][104] f16 (stride pad: 2-way free)
    float*    wT   = (float*)   (sw + 3328);   // [16][17]  f32
    _Float16* h1T  = (_Float16*)(sw + 4416);   // [16][72]  f16
    _Float16* h2T  = (_Float16*)(sw + 6720);   // [16][40]  f16

    constexpr unsigned long long GS = packGS();
    constexpr unsigned GL = packGL();

    // ================= per-block prologue: B-frags + params (L2-resident) ========
    f16x8 Benc[6];
    #pragma unroll
    for (int t = 0; t < 6; ++t) {
        const int n = t*16 + l15;
        const int g = n >> 3, o = n & 7;
        const int gs = (int)((GS >> (5*g)) & 31);
        const int gl = (int)((GL >> (2*g)) & 3);
        #pragma unroll
        for (int j = 0; j < 8; ++j) {
            const int k  = quad*8 + j;
            const int ji = k - gs;
            float v = (ji >= 0 && ji < gl) ? We[(g*3 + ji)*8 + o] : 0.f;
            Benc[t][j] = (_Float16)v;
        }
    }
    f16x8 Bwa[3];
    #pragma unroll
    for (int s = 0; s < 3; ++s) {
        #pragma unroll
        for (int j = 0; j < 8; ++j) {
            const int k = s*32 + quad*8 + j;
            float v = (l15 < 12) ? Wa[k*12 + l15] : 0.f;
            Bwa[s][j] = (_Float16)v;
        }
    }
    f16x8 Bw1[12];
    #pragma unroll
    for (int t = 0; t < 4; ++t)
        #pragma unroll
        for (int s = 0; s < 3; ++s)
            #pragma unroll
            for (int j = 0; j < 8; ++j) {
                const int k = s*32 + quad*8 + j;
                Bw1[t*3 + s][j] = (_Float16)W1[k*64 + t*16 + l15];
            }
    f16x8 Bw2[4];
    #pragma unroll
    for (int t = 0; t < 2; ++t)
        #pragma unroll
        for (int s = 0; s < 2; ++s)
            #pragma unroll
            for (int j = 0; j < 8; ++j) {
                const int k = s*32 + quad*8 + j;
                Bw2[t*2 + s][j] = (_Float16)W2[k*32 + t*16 + l15];
            }
    f16x8 Bw3;
    #pragma unroll
    for (int j = 0; j < 8; ++j)
        Bw3[j] = (_Float16)W3[(quad*8 + j)*16 + l15];

    // per-lane params (indexed by output col n = lane&15 within each 16-block)
    float encB[6], encS[6], encT[6];
    #pragma unroll
    for (int t = 0; t < 6; ++t) {
        const int c = t*16 + l15;
        float s = eg[c] * rsqrtf(ev[c] + EPS);
        encS[t] = s; encT[t] = ebt[c] - em[c]*s; encB[t] = be[c];
    }
    const float baL = (l15 < 12) ? ba[l15] : -1e4f;   // pad cols -> softmax weight 0
    float b1L[4], s1L[4], t1L[4];
    #pragma unroll
    for (int t = 0; t < 4; ++t) {
        const int c = t*16 + l15;
        float s = g1[c] * rsqrtf(v1[c] + EPS);
        s1L[t] = s; t1L[t] = bb1[c] - m1[c]*s; b1L[t] = b1[c];
    }
    float b2L[2], s2L[2], t2L[2];
    #pragma unroll
    for (int t = 0; t < 2; ++t) {
        const int c = t*16 + l15;
        float s = g2[c] * rsqrtf(v2[c] + EPS);
        s2L[t] = s; t2L[t] = bb2[c] - m2[c]*s; b2L[t] = b2[c];
    }
    const float sv3 = g3[l15] * rsqrtf(v3[l15] + EPS);
    const float b3L = b3[l15], s3L = sv3, t3L = bb3[l15] - m3[l15]*sv3;
    const float w4L = W4[l15];
    const float b4v = b4[0];

    // ================= main loop: 32 tiles/block, waves interleaved ==============
    const int tile0 = blockIdx.x * 32;
    int tile1 = tile0 + 32; if (tile1 > ntiles) tile1 = ntiles;

    for (int tile = tile0 + wave; tile < tile1; tile += 4) {
        const int rowbase = tile << 4;

        // ---- load x A-frag: A[m=l15][k=quad*8+j], cols >=29 zero ----
        int xr = rowbase + l15; if (xr > B-1) xr = B-1;
        const float* xp = x + (size_t)xr*29 + quad*8;
        float xv[8];
        if (quad < 3) {
            #pragma unroll
            for (int j = 0; j < 8; ++j) xv[j] = xp[j];
        } else {
            #pragma unroll
            for (int j = 0; j < 5; ++j) xv[j] = xp[j];
            xv[5] = xv[6] = xv[7] = 0.f;
        }
        f16x8 ax;
        #pragma unroll
        for (int j = 0; j < 8; ++j) ax[j] = (_Float16)xv[j];

        // ---- stage 1: rep[16][96] = BNaff(relu(x @ Wenc + be)) ----
        #pragma unroll
        for (int t = 0; t < 6; ++t) {
            f32x4 c = { encB[t], encB[t], encB[t], encB[t] };
            c = __builtin_amdgcn_mfma_f32_16x16x32_f16(ax, Benc[t], c, 0, 0, 0);
            #pragma unroll
            for (int r = 0; r < 4; ++r) {
                float v = fmaf(fmaxf(c[r], 0.f), encS[t], encT[t]);
                repT[(quad*4 + r)*104 + t*16 + l15] = (_Float16)v;
            }
        }

        // ---- stage 2: logits = rep @ Wa + ba ; softmax over 12 (per quad) ----
        f32x4 c2 = { baL, baL, baL, baL };
        #pragma unroll
        for (int s = 0; s < 3; ++s) {
            f16x8 a = *(const f16x8*)(repT + l15*104 + s*32 + quad*8);
            c2 = __builtin_amdgcn_mfma_f32_16x16x32_f16(a, Bwa[s], c2, 0, 0, 0);
        }
        #pragma unroll
        for (int r = 0; r < 4; ++r) {
            float v = c2[r];
            float mx = v;
            mx = fmaxf(mx, __shfl_xor(mx, 1));
            mx = fmaxf(mx, __shfl_xor(mx, 2));
            mx = fmaxf(mx, __shfl_xor(mx, 4));
            mx = fmaxf(mx, __shfl_xor(mx, 8));
            float e = __expf(v - mx);
            float sm = e;
            sm += __shfl_xor(sm, 1);
            sm += __shfl_xor(sm, 2);
            sm += __shfl_xor(sm, 4);
            sm += __shfl_xor(sm, 8);
            wT[(quad*4 + r)*17 + l15] = e * rcp_fast(sm);
        }

        // ---- stage 3: h1 = BNaff(relu((rep .* w_group) @ W1 + b1)) ----
        // A-frag k-range s*32+quad*8..+7 -> group g = s*4+quad constant per frag
        f32x4 c3[4];
        #pragma unroll
        for (int t = 0; t < 4; ++t) c3[t] = { b1L[t], b1L[t], b1L[t], b1L[t] };
        #pragma unroll
        for (int s = 0; s < 3; ++s) {
            f16x8 a = *(const f16x8*)(repT + l15*104 + s*32 + quad*8);
            _Float16 wh = (_Float16)wT[l15*17 + s*4 + quad];
            f16x8 aw;
            #pragma unroll
            for (int j = 0; j < 8; ++j) aw[j] = a[j] * wh;
            #pragma unroll
            for (int t = 0; t < 4; ++t)
                c3[t] = __builtin_amdgcn_mfma_f32_16x16x32_f16(aw, Bw1[t*3 + s], c3[t], 0, 0, 0);
        }
        #pragma unroll
        for (int t = 0; t < 4; ++t)
            #pragma unroll
            for (int r = 0; r < 4; ++r) {
                float v = fmaf(fmaxf(c3[t][r], 0.f), s1L[t], t1L[t]);
                h1T[(quad*4 + r)*72 + t*16 + l15] = (_Float16)v;
            }

        // ---- stage 4: h2 = BNaff(relu(h1 @ W2 + b2)) ----
        f32x4 c4[2];
        #pragma unroll
        for (int t = 0; t < 2; ++t) c4[t] = { b2L[t], b2L[t], b2L[t], b2L[t] };
        #pragma unroll
        for (int s = 0; s < 2; ++s) {
            f16x8 a = *(const f16x8*)(h1T + l15*72 + s*32 + quad*8);
            #pragma unroll
            for (int t = 0; t < 2; ++t)
                c4[t] = __builtin_amdgcn_mfma_f32_16x16x32_f16(a, Bw2[t*2 + s], c4[t], 0, 0, 0);
        }
        #pragma unroll
        for (int t = 0; t < 2; ++t)
            #pragma unroll
            for (int r = 0; r < 4; ++r) {
                float v = fmaf(fmaxf(c4[t][r], 0.f), s2L[t], t2L[t]);
                h2T[(quad*4 + r)*40 + t*16 + l15] = (_Float16)v;
            }

        // ---- stage 5: h3 = BNaff(relu(h2 @ W3 + b3)) (stays in regs) ----
        f32x4 c5 = { b3L, b3L, b3L, b3L };
        {
            f16x8 a = *(const f16x8*)(h2T + l15*40 + quad*8);
            c5 = __builtin_amdgcn_mfma_f32_16x16x32_f16(a, Bw3, c5, 0, 0, 0);
        }

        // ---- stage 6: z = h3 @ W4 + b4 ; sigmoid ; store ----
        float z[4];
        #pragma unroll
        for (int r = 0; r < 4; ++r) {
            float v = fmaf(fmaxf(c5[r], 0.f), s3L, t3L);
            float p = v * w4L;
            p += __shfl_xor(p, 1);
            p += __shfl_xor(p, 2);
            p += __shfl_xor(p, 4);
            p += __shfl_xor(p, 8);
            z[r] = p;
        }
        float zi = (l15 == 0) ? z[0] : (l15 == 1) ? z[1] : (l15 == 2) ? z[2] : z[3];
        if (l15 < 4) {
            int row = rowbase + quad*4 + l15;
            if (row < B)
                out[row] = rcp_fast(1.f + __expf(-(zi + b4v)));
        }
    }
}

extern "C" void kernel_launch(void* const* d_in, const int* in_sizes, int n_in,
                              void* d_out, int out_size, void* d_ws, size_t ws_size,
                              hipStream_t stream)
{
    const float* x   = (const float*)d_in[0];
    const float* We  = (const float*)d_in[1];
    const float* be  = (const float*)d_in[2];
    const float* eg  = (const float*)d_in[3];
    const float* ebt = (const float*)d_in[4];
    const float* em  = (const float*)d_in[5];
    const float* ev  = (const float*)d_in[6];
    const float* Wa  = (const float*)d_in[7];
    const float* ba  = (const float*)d_in[8];
    const float* W1  = (const float*)d_in[9];
    const float* b1  = (const float*)d_in[10];
    const float* g1  = (const float*)d_in[11];
    const float* bb1 = (const float*)d_in[12];
    const float* m1  = (const float*)d_in[13];
    const float* v1  = (const float*)d_in[14];
    const float* W2  = (const float*)d_in[15];
    const float* b2  = (const float*)d_in[16];
    const float* g2  = (const float*)d_in[17];
    const float* bb2 = (const float*)d_in[18];
    const float* m2  = (const float*)d_in[19];
    const float* v2  = (const float*)d_in[20];
    const float* W3  = (const float*)d_in[21];
    const float* b3  = (const float*)d_in[22];
    const float* g3  = (const float*)d_in[23];
    const float* bb3 = (const float*)d_in[24];
    const float* m3  = (const float*)d_in[25];
    const float* v3  = (const float*)d_in[26];
    const float* W4  = (const float*)d_in[27];
    const float* b4  = (const float*)d_in[28];

    const int B = in_sizes[0] / 29;
    const int ntiles = (B + 15) / 16;
    const int blocks = (ntiles + 31) / 32;   // 32 tiles per block (8 per wave)

    fused_kernel<<<blocks, 256, 0, stream>>>(
        x, We, be, eg, ebt, em, ev, Wa, ba,
        W1, b1, g1, bb1, m1, v1,
        W2, b2, g2, bb2, m2, v2,
        W3, b3, g3, bb3, m3, v3,
        W4, b4, (float*)d_out, B, ntiles);
}